// Round 1
// baseline (342.215 us; speedup 1.0000x reference)
//
#include <hip/hip_runtime.h>
#include <math.h>

#define EDIM 100
#define NF 4000
#define NN 4000
#define NB 8
#define FT 40      // number of f-tiles
#define FCH 100    // f's per tile (FT*FCH == NF)

// Static device scratch (avoids relying on ws_size).
__device__ float g_P_sp[NB * NF];
__device__ float g_P_po[NB * NF];
__device__ float g_e2[NN];
__device__ float g_part[2 * NB * NN * FT];   // [score][b][n][f_tile]

// P_sp[b][f] = ||fact||^2 + ||rel_b||^2 + ||arg1_b||^2 - 2*(rel_b.frel_f + arg1_b.farg1_f)
// P_po[b][f] = ||fact||^2 + ||rel_b||^2 + ||arg2_b||^2 - 2*(rel_b.frel_f + arg2_b.farg2_f)
__global__ void precompute_P(const float* __restrict__ rel,
                             const float* __restrict__ arg1,
                             const float* __restrict__ arg2,
                             const float* __restrict__ frel,
                             const float* __restrict__ fa1,
                             const float* __restrict__ fa2) {
    int f = blockIdx.x * blockDim.x + threadIdx.x;
    int b = blockIdx.y;
    if (f >= NF) return;
    float nf = 0.f, dr = 0.f, d1 = 0.f, d2 = 0.f, qr = 0.f, q1 = 0.f, q2 = 0.f;
    #pragma unroll 4
    for (int k = 0; k < EDIM; k++) {
        float vr = frel[f * EDIM + k];
        float v1 = fa1[f * EDIM + k];
        float v2 = fa2[f * EDIM + k];
        float rb = rel[b * EDIM + k];
        float a1 = arg1[b * EDIM + k];
        float a2 = arg2[b * EDIM + k];
        nf += vr * vr + v1 * v1 + v2 * v2;
        dr = fmaf(rb, vr, dr);
        d1 = fmaf(a1, v1, d1);
        d2 = fmaf(a2, v2, d2);
        qr = fmaf(rb, rb, qr);
        q1 = fmaf(a1, a1, q1);
        q2 = fmaf(a2, a2, q2);
    }
    g_P_sp[b * NF + f] = nf + qr + q1 - 2.f * (dr + d1);
    g_P_po[b * NF + f] = nf + qr + q2 - 2.f * (dr + d2);
}

__global__ void precompute_e2(const float* __restrict__ ent) {
    int n = blockIdx.x * blockDim.x + threadIdx.x;
    if (n >= NN) return;
    const float4* ep = (const float4*)(ent + n * EDIM);
    float s = 0.f;
    #pragma unroll
    for (int i = 0; i < EDIM / 4; i++) {
        float4 v = ep[i];
        s += v.x * v.x + v.y * v.y + v.z * v.z + v.w * v.w;
    }
    g_e2[n] = s;
}

// Main: for each n, over a chunk of f's, compute g1 = ent[n].fa1[f], g2 = ent[n].fa2[f],
// fold into running minima per b. fact rows are wave-uniform -> scalar loads.
__global__ void __launch_bounds__(256) main_kernel(const float* __restrict__ ent,
                                                   const float* __restrict__ fa1,
                                                   const float* __restrict__ fa2) {
    int n = blockIdx.x * 256 + threadIdx.x;
    if (n >= NN) return;

    float e[EDIM];
    const float4* ep = (const float4*)(ent + n * EDIM);
    #pragma unroll
    for (int i = 0; i < EDIM / 4; i++) {
        float4 v = ep[i];
        e[4 * i + 0] = v.x; e[4 * i + 1] = v.y;
        e[4 * i + 2] = v.z; e[4 * i + 3] = v.w;
    }

    float msp[NB], mpo[NB];
    #pragma unroll
    for (int b = 0; b < NB; b++) { msp[b] = INFINITY; mpo[b] = INFINITY; }

    const int f0 = blockIdx.y * FCH;
    for (int ff = 0; ff < FCH; ff++) {
        const int f = f0 + ff;
        const float4* p1 = (const float4*)(fa1 + f * EDIM);
        const float4* p2 = (const float4*)(fa2 + f * EDIM);
        float g1 = 0.f, g2 = 0.f;
        #pragma unroll
        for (int i = 0; i < EDIM / 4; i++) {
            float4 a = p1[i];
            float4 c = p2[i];
            g1 = fmaf(e[4 * i + 0], a.x, g1);
            g1 = fmaf(e[4 * i + 1], a.y, g1);
            g1 = fmaf(e[4 * i + 2], a.z, g1);
            g1 = fmaf(e[4 * i + 3], a.w, g1);
            g2 = fmaf(e[4 * i + 0], c.x, g2);
            g2 = fmaf(e[4 * i + 1], c.y, g2);
            g2 = fmaf(e[4 * i + 2], c.z, g2);
            g2 = fmaf(e[4 * i + 3], c.w, g2);
        }
        // score_sp pairs with ent.fact_arg2 (g2); score_po with ent.fact_arg1 (g1)
        #pragma unroll
        for (int b = 0; b < NB; b++) {
            msp[b] = fminf(msp[b], fmaf(-2.f, g2, g_P_sp[b * NF + f]));
            mpo[b] = fminf(mpo[b], fmaf(-2.f, g1, g_P_po[b * NF + f]));
        }
    }

    const int slot = blockIdx.y;
    #pragma unroll
    for (int b = 0; b < NB; b++) {
        g_part[((0 * NB + b) * NN + n) * FT + slot] = msp[b];
        g_part[((1 * NB + b) * NN + n) * FT + slot] = mpo[b];
    }
}

__global__ void finalize(float* __restrict__ out) {
    int idx = blockIdx.x * 256 + threadIdx.x;  // over 2*NB*NN, == out layout (s*B+b)*N+n
    if (idx >= 2 * NB * NN) return;
    int n = idx % NN;
    const float* p = g_part + (size_t)idx * FT;
    float m = INFINITY;
    #pragma unroll
    for (int j = 0; j < FT; j++) m = fminf(m, p[j]);
    float d2 = fmaxf(m + g_e2[n], 0.f);
    out[idx] = expf(-0.5f * d2);
}

extern "C" void kernel_launch(void* const* d_in, const int* in_sizes, int n_in,
                              void* d_out, int out_size, void* d_ws, size_t ws_size,
                              hipStream_t stream) {
    const float* rel  = (const float*)d_in[0];
    const float* arg1 = (const float*)d_in[1];
    const float* arg2 = (const float*)d_in[2];
    const float* frel = (const float*)d_in[3];
    const float* fa1  = (const float*)d_in[4];
    const float* fa2  = (const float*)d_in[5];
    const float* ent  = (const float*)d_in[6];
    float* out = (float*)d_out;

    precompute_P<<<dim3((NF + 255) / 256, NB), 256, 0, stream>>>(rel, arg1, arg2, frel, fa1, fa2);
    precompute_e2<<<(NN + 255) / 256, 256, 0, stream>>>(ent);
    main_kernel<<<dim3((NN + 255) / 256, FT), 256, 0, stream>>>(ent, fa1, fa2);
    finalize<<<(2 * NB * NN + 255) / 256, 256, 0, stream>>>(out);
}